// Round 5
// baseline (82.735 us; speedup 1.0000x reference)
//
#include <hip/hip_runtime.h>
#include <hip/hip_bf16.h>
#include <math.h>

typedef __bf16 bf16x8 __attribute__((ext_vector_type(8)));
typedef float f32x4 __attribute__((ext_vector_type(4)));

namespace {
constexpr int BN   = 8192;   // batch columns
constexpr int DK   = 128;    // feature dim
constexpr int NCAT = 8192;   // cat rows
constexpr int SRC  = 4;      // source chunks
constexpr int RG   = 16;     // row groups (512 rows each)
constexpr int TROWS = 64;    // rows per LDS tile
constexpr int NT   = 8;      // tiles per rowgroup (512/64)
constexpr float LOG2E = 1.4426950408889634f;
}

__device__ __forceinline__ float4 ld4(const float* p) {
    return *reinterpret_cast<const float4*>(p);
}

// async 16B global -> LDS (linear dest: base + lane*16)
__device__ __forceinline__ void load_lds16(const unsigned short* g, unsigned short* l) {
    __builtin_amdgcn_global_load_lds(
        (const __attribute__((address_space(1))) void*)g,
        (__attribute__((address_space(3))) void*)l, 16, 0, 0);
}

// fp32 -> bf16 for x (row-major) and cat (tile-major, XOR-pre-swizzled so that a
// LINEAR global_load_lds produces the swizzled LDS layout the MFMA reads expect).
__global__ __launch_bounds__(256) void k_convert2(const float* __restrict__ x,
                                                  const float* __restrict__ cat,
                                                  unsigned short* __restrict__ xb,
                                                  unsigned short* __restrict__ catb) {
    const int i = blockIdx.x * 256 + threadIdx.x;
    const int nx = BN * DK / 8;
    const float* src;
    unsigned short* dst;
    int j;
    size_t dchunk;
    if (i < nx) {
        src = x; dst = xb; j = i; dchunk = (size_t)j;
    } else {
        src = cat; dst = catb; j = i - nx;
        const int r = j >> 4, c = j & 15;      // row, 16B-chunk within row
        const int rt = r >> 6, r6 = r & 63;    // 64-row tile, row within tile
        dchunk = (size_t)rt * 1024 + r6 * 16 + (c ^ (r6 & 7));
    }
    const float4 a = ld4(src + (size_t)j * 8);
    const float4 b = ld4(src + (size_t)j * 8 + 4);
    float vals[8] = {a.x, a.y, a.z, a.w, b.x, b.y, b.z, b.w};
    union { unsigned short u[8]; uint4 v; } o;
#pragma unroll
    for (int q = 0; q < 8; ++q) {
        __hip_bfloat16 h = __float2bfloat16(vals[q]);
        o.u[q] = *reinterpret_cast<unsigned short*>(&h);
    }
    *reinterpret_cast<uint4*>(&dst[dchunk * 8]) = o.v;
}

// MFMA pass over 128 cols x 512 rows. B (x) fragments in registers all kernel;
// A (cat) double-buffered in LDS via global_load_lds, one barrier per tile:
//   issue async loads(t+1) -> compute(t) -> barrier (drains loads).
// No softmax max needed: |d|/norm4 <= 1 provably (norm4 >= max|d|).
// PASS==1: outA = partial sum(d^4)
// PASS==2: outA = partial Z, outB = partial sum(y*exp); norms from pp4in in-block
template <int PASS>
__global__ __launch_bounds__(256, 4) void k_pass(
    const unsigned short* __restrict__ xb,    // [BN][DK] bf16 row-major
    const unsigned short* __restrict__ catb,  // tile-major pre-swizzled bf16
    const float* __restrict__ y,
    const float* __restrict__ pp4in,          // pass2: [RG][BN]
    float* __restrict__ outA,
    float* __restrict__ outB) {
    __shared__ __align__(16) unsigned short As[2][TROWS * DK];  // 32 KB
    __shared__ float ysh[512];
    __shared__ float nsh[128];
    __shared__ float redA[2][128];
    __shared__ float redB[2][128];

    const int t = threadIdx.x;
    const int colbase = blockIdx.x * 128;
    const int rowgrp = blockIdx.y;            // 0..15
    const int tile0 = rowgrp * NT;            // global 64-row tile index base

    const int wid = t >> 6;
    const int lane = t & 63;
    const int wr = wid >> 1;                  // row half (32 rows)
    const int wc = wid & 1;                   // col half (64 cols)
    const int lr = lane & 15;
    const int kb = lane >> 4;                 // k-block 0..3

    // issue tile-0 async loads immediately (latency hidden under prologue)
#pragma unroll
    for (int q = 0; q < 4; ++q)
        load_lds16(catb + ((size_t)tile0 * 1024 + (wid * 4 + q) * 64 + lane) * 8,
                   &As[0][(wid * 4 + q) * 64 * 8]);

    // B fragments: 16 x bf16x8 (64 VGPR), from global (L2-hit), once
    bf16x8 Bf[4][4];
#pragma unroll
    for (int j = 0; j < 4; ++j)
#pragma unroll
        for (int kk = 0; kk < 4; ++kk)
            Bf[j][kk] = *reinterpret_cast<const bf16x8*>(
                &xb[(size_t)(colbase + wc * 64 + j * 16 + lr) * DK + kk * 32 + kb * 8]);

    if (PASS == 2) {
        if (t < 128) {
            float sp = 0.f;
#pragma unroll
            for (int r = 0; r < RG; ++r) sp += pp4in[r * BN + colbase + t];
            nsh[t] = LOG2E / fmaxf(sqrtf(sqrtf(sp)), 1e-12f);
        }
#pragma unroll
        for (int q = t; q < 512; q += 256) ysh[q] = y[rowgrp * 512 + q];
    }
    __syncthreads();

    float inm[4];
    if (PASS == 2) {
#pragma unroll
        for (int j = 0; j < 4; ++j) inm[j] = nsh[wc * 64 + j * 16 + lr];
    }

    float accA[4] = {0.f, 0.f, 0.f, 0.f};
    float accB[4] = {0.f, 0.f, 0.f, 0.f};

    for (int tl = 0; tl < NT; ++tl) {
        const int cur = tl & 1, nxt = cur ^ 1;
        if (tl < NT - 1) {  // async-stage next tile; completes at the barrier
#pragma unroll
            for (int q = 0; q < 4; ++q)
                load_lds16(catb + ((size_t)(tile0 + tl + 1) * 1024 +
                                   (wid * 4 + q) * 64 + lane) * 8,
                           &As[nxt][(wid * 4 + q) * 64 * 8]);
        }

        f32x4 acc[2][4];
#pragma unroll
        for (int i = 0; i < 2; ++i)
#pragma unroll
            for (int j = 0; j < 4; ++j) acc[i][j] = (f32x4){0.f, 0.f, 0.f, 0.f};

#pragma unroll
        for (int kk = 0; kk < 4; ++kk) {
            bf16x8 a[2];
#pragma unroll
            for (int i = 0; i < 2; ++i) {
                const int row = wr * 32 + i * 16 + lr;
                const int chunk = (kk * 4 + kb) ^ (lr & 7);
                a[i] = *reinterpret_cast<const bf16x8*>(&As[cur][row * 128 + chunk * 8]);
            }
#pragma unroll
            for (int i = 0; i < 2; ++i)
#pragma unroll
                for (int j = 0; j < 4; ++j)
                    acc[i][j] = __builtin_amdgcn_mfma_f32_16x16x32_bf16(
                        a[i], Bf[j][kk], acc[i][j], 0, 0, 0);
        }

        if (PASS == 1) {
#pragma unroll
            for (int i = 0; i < 2; ++i)
#pragma unroll
                for (int j = 0; j < 4; ++j)
#pragma unroll
                    for (int r = 0; r < 4; ++r) {
                        const float v = acc[i][j][r];
                        const float v2 = v * v;
                        accA[j] = fmaf(v2, v2, accA[j]);
                    }
        } else {
#pragma unroll
            for (int i = 0; i < 2; ++i) {
                const float4 yv =
                    *reinterpret_cast<const float4*>(&ysh[tl * 64 + wr * 32 + i * 16 + kb * 4]);
                const float yr4[4] = {yv.x, yv.y, yv.z, yv.w};
#pragma unroll
                for (int r = 0; r < 4; ++r) {
                    const float yr = yr4[r];
#pragma unroll
                    for (int j = 0; j < 4; ++j) {
                        const float e = exp2f(acc[i][j][r] * inm[j]);
                        accA[j] += e;
                        accB[j] = fmaf(yr, e, accB[j]);
                    }
                }
            }
        }
        __syncthreads();  // drains async loads; As[nxt] ready
    }

    // reduce over k-block groups (lane bits 4-5)
#pragma unroll
    for (int j = 0; j < 4; ++j) {
        accA[j] += __shfl_xor(accA[j], 16, 64);
        accA[j] += __shfl_xor(accA[j], 32, 64);
        if (PASS == 2) {
            accB[j] += __shfl_xor(accB[j], 16, 64);
            accB[j] += __shfl_xor(accB[j], 32, 64);
        }
    }
    if (lane < 16) {
#pragma unroll
        for (int j = 0; j < 4; ++j) {
            redA[wr][wc * 64 + j * 16 + lane] = accA[j];
            if (PASS == 2) redB[wr][wc * 64 + j * 16 + lane] = accB[j];
        }
    }
    __syncthreads();
    if (t < 128) {
        outA[(size_t)rowgrp * BN + colbase + t] = redA[0][t] + redA[1][t];
        if (PASS == 2)
            outB[(size_t)rowgrp * BN + colbase + t] = redB[0][t] + redB[1][t];
    }
}

// Final: 4 threads per output (one per source), xor-reduce
__global__ __launch_bounds__(256) void k_final(const float* __restrict__ x,
                                               const float* __restrict__ phi,
                                               const float* __restrict__ pZ,
                                               const float* __restrict__ pW,
                                               const float* __restrict__ bias,
                                               float* __restrict__ out) {
    const int g = blockIdx.x * 256 + threadIdx.x;
    const int b = g >> 2, s = g & 3;
    float dot = 0.f;
#pragma unroll
    for (int k = 0; k < DK; k += 4) {
        const float4 xv = ld4(&x[(size_t)b * DK + k]);
        const float4 pv = ld4(&phi[s * DK + k]);
        dot += xv.x * pv.x + xv.y * pv.y + xv.z * pv.z + xv.w * pv.w;
    }
    float W = 0.f, Z = 0.f;
#pragma unroll
    for (int r = 0; r < 4; ++r) {
        W += pW[(size_t)(4 * s + r) * BN + b];
        Z += pZ[(size_t)(4 * s + r) * BN + b];
    }
    float v = __expf(dot) * W;
    v += __shfl_xor(v, 1, 64);
    v += __shfl_xor(v, 2, 64);
    Z += __shfl_xor(Z, 1, 64);
    Z += __shfl_xor(Z, 2, 64);
    if (s == 0) out[b] = v / Z + bias[0];
}

extern "C" void kernel_launch(void* const* d_in, const int* in_sizes, int n_in,
                              void* d_out, int out_size, void* d_ws, size_t ws_size,
                              hipStream_t stream) {
    const float* x    = (const float*)d_in[0];
    const float* cat  = (const float*)d_in[1];
    const float* y    = (const float*)d_in[2];
    const float* phi  = (const float*)d_in[3];
    const float* bias = (const float*)d_in[4];
    float* out = (float*)d_out;

    char* ws = (char*)d_ws;
    unsigned short* xb   = (unsigned short*)ws;            // BN*DK bf16 (2MB)
    unsigned short* catb = xb + (size_t)BN * DK;           // 2MB, pre-swizzled
    float* pp4 = (float*)(catb + (size_t)NCAT * DK);       // RG*BN
    float* pZ  = pp4 + (size_t)RG * BN;                    // RG*BN
    float* pW  = pZ + (size_t)RG * BN;                     // RG*BN

    k_convert2<<<(BN * DK + NCAT * DK) / 8 / 256, 256, 0, stream>>>(x, cat, xb, catb);
    k_pass<1><<<dim3(BN / 128, RG), 256, 0, stream>>>(xb, catb, y, nullptr, pp4, nullptr);
    k_pass<2><<<dim3(BN / 128, RG), 256, 0, stream>>>(xb, catb, y, pp4, pZ, pW);
    k_final<<<BN * SRC / 256, 256, 0, stream>>>(x, phi, pZ, pW, bias, out);
}

// Round 6
// 64.976 us; speedup vs baseline: 1.2733x; 1.2733x over previous
//
#include <hip/hip_runtime.h>
#include <hip/hip_bf16.h>
#include <math.h>

typedef __bf16 bf16x8 __attribute__((ext_vector_type(8)));
typedef float f32x4 __attribute__((ext_vector_type(4)));

namespace {
constexpr int BN   = 8192;   // batch columns
constexpr int DK   = 128;    // feature dim
constexpr int NCAT = 8192;   // cat rows
constexpr int SRC  = 4;      // source chunks
constexpr int RG   = 16;     // row groups (512 rows each)
constexpr int TROWS = 64;    // rows per LDS tile
constexpr int NT   = 8;      // tiles per rowgroup (512/64)
constexpr float LOG2E = 1.4426950408889634f;
}

__device__ __forceinline__ float4 ld4(const float* p) {
    return *reinterpret_cast<const float4*>(p);
}

// async 16B global -> LDS (linear dest: base + lane*16)
__device__ __forceinline__ void load_lds16(const unsigned short* g, unsigned short* l) {
    __builtin_amdgcn_global_load_lds(
        (const __attribute__((address_space(1))) void*)g,
        (__attribute__((address_space(3))) void*)l, 16, 0, 0);
}

// fp32 -> bf16 for x (row-major) and cat (tile-major, XOR-pre-swizzled so that a
// LINEAR global_load_lds produces the swizzled LDS layout the MFMA reads expect).
__global__ __launch_bounds__(256) void k_convert2(const float* __restrict__ x,
                                                  const float* __restrict__ cat,
                                                  unsigned short* __restrict__ xb,
                                                  unsigned short* __restrict__ catb) {
    const int i = blockIdx.x * 256 + threadIdx.x;
    const int nx = BN * DK / 8;
    const float* src;
    unsigned short* dst;
    int j;
    size_t dchunk;
    if (i < nx) {
        src = x; dst = xb; j = i; dchunk = (size_t)j;
    } else {
        src = cat; dst = catb; j = i - nx;
        const int r = j >> 4, c = j & 15;      // row, 16B-chunk within row
        const int rt = r >> 6, r6 = r & 63;    // 64-row tile, row within tile
        dchunk = (size_t)rt * 1024 + r6 * 16 + (c ^ (r6 & 7));
    }
    const float4 a = ld4(src + (size_t)j * 8);
    const float4 b = ld4(src + (size_t)j * 8 + 4);
    float vals[8] = {a.x, a.y, a.z, a.w, b.x, b.y, b.z, b.w};
    union { unsigned short u[8]; uint4 v; } o;
#pragma unroll
    for (int q = 0; q < 8; ++q) {
        __hip_bfloat16 h = __float2bfloat16(vals[q]);
        o.u[q] = *reinterpret_cast<unsigned short*>(&h);
    }
    *reinterpret_cast<uint4*>(&dst[dchunk * 8]) = o.v;
}

// MFMA pass over 128 cols x 512 rows. Each of 4 waves owns a 32-col quarter
// (Bf [2][4] = 32 VGPR) x all 64 tile rows. A (cat) double-buffered in LDS via
// global_load_lds: issue async(t+1) -> compute(t) -> barrier.
// No softmax max needed: |d|/norm4 <= 1 provably (norm4 >= max|d|).
// PASS==1: outA = partial sum(d^4)
// PASS==2: outA = partial Z, outB = partial sum(y*exp); norms from pp4in in-block
template <int PASS>
__global__ __launch_bounds__(256, 4) void k_pass(
    const unsigned short* __restrict__ xb,    // [BN][DK] bf16 row-major
    const unsigned short* __restrict__ catb,  // tile-major pre-swizzled bf16
    const float* __restrict__ y,
    const float* __restrict__ pp4in,          // pass2: [RG][BN]
    float* __restrict__ outA,
    float* __restrict__ outB) {
    __shared__ __align__(16) unsigned short As[2][TROWS * DK];  // 32 KB
    __shared__ float ysh[512];
    __shared__ float nsh[128];

    const int t = threadIdx.x;
    const int colbase = blockIdx.x * 128;
    const int rowgrp = blockIdx.y;            // 0..15
    const int tile0 = rowgrp * NT;            // global 64-row tile index base

    const int wid = t >> 6;                   // wave owns cols wid*32..wid*32+31
    const int lane = t & 63;
    const int lr = lane & 15;
    const int kb = lane >> 4;                 // k-block 0..3

    // issue tile-0 async loads immediately
#pragma unroll
    for (int q = 0; q < 4; ++q)
        load_lds16(catb + ((size_t)tile0 * 1024 + (wid * 4 + q) * 64 + lane) * 8,
                   &As[0][(wid * 4 + q) * 64 * 8]);

    // B fragments: 8 x bf16x8 (32 VGPR), from global (L2-hit), once
    bf16x8 Bf[2][4];
#pragma unroll
    for (int j = 0; j < 2; ++j)
#pragma unroll
        for (int kk = 0; kk < 4; ++kk)
            Bf[j][kk] = *reinterpret_cast<const bf16x8*>(
                &xb[(size_t)(colbase + wid * 32 + j * 16 + lr) * DK + kk * 32 + kb * 8]);

    if (PASS == 2) {
        if (t < 128) {
            float sp = 0.f;
#pragma unroll
            for (int r = 0; r < RG; ++r) sp += pp4in[r * BN + colbase + t];
            nsh[t] = LOG2E / fmaxf(sqrtf(sqrtf(sp)), 1e-12f);
        }
#pragma unroll
        for (int q = t; q < 512; q += 256) ysh[q] = y[rowgrp * 512 + q];
    }
    __syncthreads();

    float inm[2];
    if (PASS == 2) {
#pragma unroll
        for (int j = 0; j < 2; ++j) inm[j] = nsh[wid * 32 + j * 16 + lr];
    }

    float accA[2] = {0.f, 0.f};
    float accB[2] = {0.f, 0.f};

    for (int tl = 0; tl < NT; ++tl) {
        const int cur = tl & 1, nxt = cur ^ 1;
        if (tl < NT - 1) {  // async-stage next tile; completes at the barrier
#pragma unroll
            for (int q = 0; q < 4; ++q)
                load_lds16(catb + ((size_t)(tile0 + tl + 1) * 1024 +
                                   (wid * 4 + q) * 64 + lane) * 8,
                           &As[nxt][(wid * 4 + q) * 64 * 8]);
        }

        f32x4 acc[4][2];
#pragma unroll
        for (int i = 0; i < 4; ++i)
#pragma unroll
            for (int j = 0; j < 2; ++j) acc[i][j] = (f32x4){0.f, 0.f, 0.f, 0.f};

#pragma unroll
        for (int kk = 0; kk < 4; ++kk) {
            bf16x8 a[4];
#pragma unroll
            for (int i = 0; i < 4; ++i) {
                const int row = i * 16 + lr;
                const int chunk = (kk * 4 + kb) ^ (lr & 7);
                a[i] = *reinterpret_cast<const bf16x8*>(&As[cur][row * 128 + chunk * 8]);
            }
#pragma unroll
            for (int i = 0; i < 4; ++i)
#pragma unroll
                for (int j = 0; j < 2; ++j)
                    acc[i][j] = __builtin_amdgcn_mfma_f32_16x16x32_bf16(
                        a[i], Bf[j][kk], acc[i][j], 0, 0, 0);
        }

        if (PASS == 1) {
#pragma unroll
            for (int i = 0; i < 4; ++i)
#pragma unroll
                for (int j = 0; j < 2; ++j)
#pragma unroll
                    for (int r = 0; r < 4; ++r) {
                        const float v = acc[i][j][r];
                        const float v2 = v * v;
                        accA[j] = fmaf(v2, v2, accA[j]);
                    }
        } else {
#pragma unroll
            for (int i = 0; i < 4; ++i) {
                const float4 yv =
                    *reinterpret_cast<const float4*>(&ysh[tl * 64 + i * 16 + kb * 4]);
                const float yr4[4] = {yv.x, yv.y, yv.z, yv.w};
#pragma unroll
                for (int r = 0; r < 4; ++r) {
                    const float yr = yr4[r];
#pragma unroll
                    for (int j = 0; j < 2; ++j) {
                        const float e = exp2f(acc[i][j][r] * inm[j]);
                        accA[j] += e;
                        accB[j] = fmaf(yr, e, accB[j]);
                    }
                }
            }
        }
        __syncthreads();  // drains async loads; As[nxt] ready
    }

    // reduce over k-block groups (lane bits 4-5); columns are wave-private
#pragma unroll
    for (int j = 0; j < 2; ++j) {
        accA[j] += __shfl_xor(accA[j], 16, 64);
        accA[j] += __shfl_xor(accA[j], 32, 64);
        if (PASS == 2) {
            accB[j] += __shfl_xor(accB[j], 16, 64);
            accB[j] += __shfl_xor(accB[j], 32, 64);
        }
    }
    if (lane < 16) {
#pragma unroll
        for (int j = 0; j < 2; ++j) {
            const int col = colbase + wid * 32 + j * 16 + lane;
            outA[(size_t)rowgrp * BN + col] = accA[j];
            if (PASS == 2) outB[(size_t)rowgrp * BN + col] = accB[j];
        }
    }
}

// Final: 4 threads per output (one per source), xor-reduce
__global__ __launch_bounds__(256) void k_final(const float* __restrict__ x,
                                               const float* __restrict__ phi,
                                               const float* __restrict__ pZ,
                                               const float* __restrict__ pW,
                                               const float* __restrict__ bias,
                                               float* __restrict__ out) {
    const int g = blockIdx.x * 256 + threadIdx.x;
    const int b = g >> 2, s = g & 3;
    float dot = 0.f;
#pragma unroll
    for (int k = 0; k < DK; k += 4) {
        const float4 xv = ld4(&x[(size_t)b * DK + k]);
        const float4 pv = ld4(&phi[s * DK + k]);
        dot += xv.x * pv.x + xv.y * pv.y + xv.z * pv.z + xv.w * pv.w;
    }
    float W = 0.f, Z = 0.f;
#pragma unroll
    for (int r = 0; r < 4; ++r) {
        W += pW[(size_t)(4 * s + r) * BN + b];
        Z += pZ[(size_t)(4 * s + r) * BN + b];
    }
    float v = __expf(dot) * W;
    v += __shfl_xor(v, 1, 64);
    v += __shfl_xor(v, 2, 64);
    Z += __shfl_xor(Z, 1, 64);
    Z += __shfl_xor(Z, 2, 64);
    if (s == 0) out[b] = v / Z + bias[0];
}

extern "C" void kernel_launch(void* const* d_in, const int* in_sizes, int n_in,
                              void* d_out, int out_size, void* d_ws, size_t ws_size,
                              hipStream_t stream) {
    const float* x    = (const float*)d_in[0];
    const float* cat  = (const float*)d_in[1];
    const float* y    = (const float*)d_in[2];
    const float* phi  = (const float*)d_in[3];
    const float* bias = (const float*)d_in[4];
    float* out = (float*)d_out;

    char* ws = (char*)d_ws;
    unsigned short* xb   = (unsigned short*)ws;            // BN*DK bf16 (2MB)
    unsigned short* catb = xb + (size_t)BN * DK;           // 2MB, pre-swizzled
    float* pp4 = (float*)(catb + (size_t)NCAT * DK);       // RG*BN
    float* pZ  = pp4 + (size_t)RG * BN;                    // RG*BN
    float* pW  = pZ + (size_t)RG * BN;                     // RG*BN

    k_convert2<<<(BN * DK + NCAT * DK) / 8 / 256, 256, 0, stream>>>(x, cat, xb, catb);
    k_pass<1><<<dim3(BN / 128, RG), 256, 0, stream>>>(xb, catb, y, nullptr, pp4, nullptr);
    k_pass<2><<<dim3(BN / 128, RG), 256, 0, stream>>>(xb, catb, y, pp4, pZ, pW);
    k_final<<<BN * SRC / 256, 256, 0, stream>>>(x, phi, pZ, pW, bias, out);
}